// Round 3
// baseline (179.444 us; speedup 1.0000x reference)
//
#include <hip/hip_runtime.h>
#include <math.h>

// Round 5: bpermute-throughput attack.
//  - 2 px/lane (128-wide strip): pair-shared lane exchanges (8->4, 4->2, 8->4)
//  - pre-shifted mag rings: NMS needs 0 bpermutes (was 6)
//  - all bpermute results consumed one iteration later (loop-carried) -> one
//    lgkmcnt wait per iter, full-iteration latency in flight
//  => 12 bperms / iter / wave for 2 px (was 16 for 1 px)
#define IMW 512
#define SEG 32
#define NSEG (512/SEG)      // 16
#define NSTRIP 5            // 5*116 = 580 >= 512
#define OUTW 116

__device__ __forceinline__ int reflect512(int i) {   // valid for i in [-511,1022]
    int a = i < 0 ? -i : i;
    int b = 1022 - a;
    return a < b ? a : b;
}
__device__ __forceinline__ float bperm(int a4, float v) {
    return __int_as_float(__builtin_amdgcn_ds_bpermute(a4, __float_as_int(v)));
}

__global__ __launch_bounds__(128)
void canny_pipe2(const float* __restrict__ x, float* __restrict__ out) {
    const int lane = threadIdx.x & 63;
    const int unit = __builtin_amdgcn_readfirstlane(
                         (int)(blockIdx.x * 2 + (threadIdx.x >> 6)));
    const int img   = unit / (NSTRIP * NSEG);
    const int rem   = unit - img * (NSTRIP * NSEG);
    const int strip = rem / NSEG;
    const int seg   = rem - strip * NSEG;
    const int Y0 = seg * SEG, Y1 = Y0 + SEG;
    const int xbase = strip * OUTW - 6;
    const int xa = xbase + 2 * lane, xb = xa + 1;    // element columns (a even)
    const int xra = reflect512(xa), xrb = reflect512(xb);
    const bool inA = (xa >= 0) && (xa < IMW);
    const bool inB = (xb >= 0) && (xb < IMW);
    const bool stl = (lane >= 3) && (lane < 61) && (xb < IMW);
    const int lm4 = ((lane - 1) & 63) << 2;          // lane L-1 byte addr
    const int lp4 = ((lane + 1) & 63) << 2;          // lane L+1
    const bool clampL = (xa == 0);                   // sobel edge-pad x left
    const bool clampR = (xb == IMW - 1);             // sobel edge-pad x right

    const float* base = x + (size_t)img * 3 * IMW * IMW;
    const float* b0 = base + (size_t)reflect512(Y0 - 6) * IMW;
    const float* b1 = b0 + (size_t)IMW * IMW;
    const float* b2 = b0 + (size_t)2 * IMW * IMW;
    float* ob = out + (size_t)img * IMW * IMW;

    const float K0 = 0.054488684549643f, K1 = 0.244201342003233f, K2 = 0.402619946931554f;

    // ring buffers (per element a/b); row labels at iteration v:
    float h0a=0,h1a=0,h2a=0,h3a=0,h4a=0, h0b=0,h1b=0,h2b=0,h3b=0,h4b=0; // hb rows v-5..v-1
    float hxA0=0,hxA1=0,hxA2=0, hxB0=0,hxB1=0,hxB2=0;                   // hx rows v-6..v-4
    float hyA0=0,hyA1=0,hyA2=0, hyB0=0,hyB1=0,hyB2=0;
    float mgA0=0,mgA1=0,mgA2=0, mgB0=0,mgB1=0,mgB2=0;                   // mag rows v-8..v-6 (pre-push)
    float smM0=0,smM1=0,smM2=0, smP0=0,smP1=0,smP2=0;                   // shifted mag rows v-8..v-6 (post-push)
    int   axA0=0,axA1=0,axA2=0, axB0=0,axB1=0,axB2=0;                   // axis rows v-8..v-6 (pre-push)
    float cmA0=0,cmA1=0,cmA2=0,cmA3=0,cmA4=0;                           // colmax rows v-12..v-8 (post-push)
    float cmB0=0,cmB1=0,cmB2=0,cmB3=0,cmB4=0;
    // previous-row values (exchange partners held locally)
    float pga=0, pgb=0;    // gray row v-1
    float pba=0, pbb=0;    // blur row v-4
    float psa=0, psb=0;    // msk  row v-8
    // loop-carried bpermute results (issued iter v-1, consumed iter v)
    float qg_am=0, qg_ap=0, qg_bm=0, qg_bp=0;   // gray[v-1] a/b from L-/L+
    float qb_bm=0, qb_ap=0;                     // blur[v-4]: b from L-, a from L+
    float qm_bm=0, qm_ap=0;                     // mag [v-6]: b from L-, a from L+
    float qs_am=0, qs_ap=0, qs_bm=0, qs_bp=0;   // msk [v-8] a/b from L-/L+

    // prefetch gray source row v = Y0-6
    float f0a = b0[xra], f0b = b0[xrb];
    float f1a = b1[xra], f1b = b1[xrb];
    float f2a = b2[xra], f2b = b2[xrb];

    #pragma unroll 4
    for (int v = Y0 - 6; v <= Y1 + 9; ++v) {
        // ---- [1] gray row v; advance pointers (reflect walks +-1 row), prefetch v+1
        float ga = 0.299f * f2a + 0.587f * f1a + 0.114f * f0a;
        float gb = 0.299f * f2b + 0.587f * f1b + 0.114f * f0b;
        const int d = ((unsigned)v <= 510u) ? IMW : -IMW;     // scalar
        b0 += d; b1 += d; b2 += d;
        f0a = b0[xra]; f0b = b0[xrb];
        f1a = b1[xra]; f1b = b1[xrb];
        f2a = b2[xra]; f2b = b2[xrb];

        // ---- [2] h-blur row v-1 (consume gray shifts issued last iter)
        // e0 taps x-2,x-1,+1,+2 = a(L-1), b(L-1), own b, a(L+1)
        float hba = K0 * (qg_am + qg_ap) + K1 * (qg_bm + pgb) + K2 * pga;
        float hbb = K0 * (qg_bm + qg_bp) + K1 * (pga + qg_ap) + K2 * pgb;
        pga = ga; pgb = gb;
        qg_am = bperm(lm4, ga); qg_ap = bperm(lp4, ga);
        qg_bm = bperm(lm4, gb); qg_bp = bperm(lp4, gb);
        h0a=h1a; h1a=h2a; h2a=h3a; h3a=h4a; h4a=hba;
        h0b=h1b; h1b=h2b; h2b=h3b; h3b=h4b; h4b=hbb;

        // ---- [3] v-blur -> blur row v-3
        float bla = K0 * (h0a + h4a) + K1 * (h1a + h3a) + K2 * h2a;
        float blb = K0 * (h0b + h4b) + K1 * (h1b + h3b) + K2 * h2b;

        // ---- [4] NMS at m = v-7 (zero extra bperms: pre-shifted rings)
        smM0=smM1; smM1=smM2; smM2=qm_bm;   // shifted mag row v-6 lands
        smP0=smP1; smP1=smP2; smP2=qm_ap;
        {
            const int m = v - 7;
            // row m-1 / m+1 with y zero-pad (scalar conditions)
            float m0a = (m==0)?0.f:mgA0, m0b = (m==0)?0.f:mgB0;
            float s0m = (m==0)?0.f:smM0, s0p = (m==0)?0.f:smP0;
            float m2a = (m==511)?0.f:mgA2, m2b = (m==511)?0.f:mgB2;
            float s2m = (m==511)?0.f:smM2, s2p = (m==511)?0.f:smP2;
            // element a
            const int da = axA1;
            float mpa = (da==0) ? mgB1 : (da==1) ? m2b : (da==2) ? m2a : s2m;
            float mna = (da==0) ? smM1 : (da==1) ? s0m : (da==2) ? m0a : m0b;
            float cena = mgA1;
            float mska_ = (inA && fminf(cena - mpa, cena - mna) > 0.f) ? cena : 0.f;
            // element b
            const int db = axB1;
            float mpb = (db==0) ? smP1 : (db==1) ? s2p : (db==2) ? m2b : m2a;
            float mnb = (db==0) ? mgA1 : (db==1) ? m0a : (db==2) ? m0b : s0p;
            float cenb = mgB1;
            float mskb_ = (inB && fminf(cenb - mpb, cenb - mnb) > 0.f) ? cenb : 0.f;

            // ---- [7] colmax at c = v-8 (consume msk shifts issued last iter)
            // e0 taps: a(L-1), b(L-1), own a, own b, a(L+1)
            float cma = fmaxf(fmaxf(qs_am, qs_bm), fmaxf(fmaxf(psa, psb), qs_ap));
            // e1 taps: b(L-1), own a, own b, a(L+1), b(L+1)
            float cmb = fmaxf(fmaxf(qs_bm, psa), fmaxf(fmaxf(psb, qs_ap), qs_bp));
            cmA0=cmA1; cmA1=cmA2; cmA2=cmA3; cmA3=cmA4; cmA4=cma;
            cmB0=cmB1; cmB1=cmB2; cmB2=cmB3; cmB3=cmB4; cmB4=cmb;
            psa = mska_; psb = mskb_;
            qs_am = bperm(lm4, mska_); qs_ap = bperm(lp4, mska_);
            qs_bm = bperm(lm4, mskb_); qs_bp = bperm(lp4, mskb_);
        }

        // ---- [5] sobel h-pass row v-4 (consume blur shifts issued last iter)
        {
            float la = clampL ? pba : qb_bm;   // left of e0 (edge pad)
            float ra = pbb;                    // right of e0 = own b
            float lb = pba;                    // left of e1 = own a
            float rb = clampR ? pbb : qb_ap;   // right of e1 (edge pad)
            float nxa = ra - la, nya = la + 2.f * pba + ra;
            float nxb = rb - lb, nyb = lb + 2.f * pbb + rb;
            hxA0=hxA1; hxA1=hxA2; hxA2=nxa;  hxB0=hxB1; hxB1=hxB2; hxB2=nxb;
            hyA0=hyA1; hyA1=hyA2; hyA2=nya;  hyB0=hyB1; hyB1=hyB2; hyB2=nyb;
            pba = bla; pbb = blb;
            qb_bm = bperm(lm4, blb); qb_ap = bperm(lp4, bla);
        }

        // ---- [6] sobel v-pass at g = v-5 -> mag/axis; push rings; issue mag shifts
        {
            const int g = v - 5;
            float hxaa = (g==0) ? hxA1 : hxA0;  float hxca = (g==511) ? hxA1 : hxA2;
            float hyaa = (g==0) ? hyA1 : hyA0;  float hyca = (g==511) ? hyA1 : hyA2;
            float gxa = (hxaa + 2.f * hxA1 + hxca) * 0.125f;
            float gya = (hyca - hyaa) * 0.125f;
            float maga = sqrtf(gxa * gxa + gya * gya + 1e-6f);
            float axma = fabsf(gxa), ayma = fabsf(gya);
            int aa;
            if (ayma <= 0.41421356237309515f * axma)      aa = 0;
            else if (ayma >= 2.4142135623730951f * axma)  aa = 2;
            else aa = ((gxa >= 0.f) == (gya >= 0.f)) ? 1 : 3;

            float hxab = (g==0) ? hxB1 : hxB0;  float hxcb = (g==511) ? hxB1 : hxB2;
            float hyab = (g==0) ? hyB1 : hyB0;  float hycb = (g==511) ? hyB1 : hyB2;
            float gxb = (hxab + 2.f * hxB1 + hxcb) * 0.125f;
            float gyb = (hycb - hyab) * 0.125f;
            float magb = sqrtf(gxb * gxb + gyb * gyb + 1e-6f);
            float axmb = fabsf(gxb), aymb = fabsf(gyb);
            int ab;
            if (aymb <= 0.41421356237309515f * axmb)      ab = 0;
            else if (aymb >= 2.4142135623730951f * axmb)  ab = 2;
            else ab = ((gxb >= 0.f) == (gyb >= 0.f)) ? 1 : 3;

            mgA0=mgA1; mgA1=mgA2; mgA2 = inA ? maga : 0.f;
            mgB0=mgB1; mgB1=mgB2; mgB2 = inB ? magb : 0.f;
            axA0=axA1; axA1=axA2; axA2=aa;
            axB0=axB1; axB1=axB2; axB2=ab;
            qm_bm = bperm(lm4, mgB2); qm_ap = bperm(lp4, mgA2);
        }

        // ---- [8] out row y = v-10 (vertical 5-max, zero-pad y)
        {
            const int y = v - 10;
            if (y >= Y0) {
                float c0a=(y>=2)?cmA0:0.f, c1a=(y>=1)?cmA1:0.f;
                float c3a=(y<=510)?cmA3:0.f, c4a=(y<=509)?cmA4:0.f;
                float va = fmaxf(fmaxf(fmaxf(c0a, c1a), fmaxf(cmA2, c3a)), c4a);
                float c0b=(y>=2)?cmB0:0.f, c1b=(y>=1)?cmB1:0.f;
                float c3b=(y<=510)?cmB3:0.f, c4b=(y<=509)?cmB4:0.f;
                float vb = fmaxf(fmaxf(fmaxf(c0b, c1b), fmaxf(cmB2, c3b)), c4b);
                if (stl) {
                    float2 t; t.x = va; t.y = vb;
                    *(float2*)(ob + (size_t)y * IMW + xa) = t;
                }
            }
        }
    }
}

extern "C" void kernel_launch(void* const* d_in, const int* in_sizes, int n_in,
                              void* d_out, int out_size, void* d_ws, size_t ws_size,
                              hipStream_t stream) {
    const float* x = (const float*)d_in[0];
    float* out = (float*)d_out;
    const int units = 32 * NSTRIP * NSEG;   // 2560 waves
    dim3 grid(units / 2);                   // 2 waves per 128-thread block
    canny_pipe2<<<grid, 128, 0, stream>>>(x, out);
}

// Round 4
// 177.615 us; speedup vs baseline: 1.0103x; 1.0103x over previous
//
#include <hip/hip_runtime.h>
#include <math.h>

// Round 6: DPP wave-shift attack. All lane exchanges are +-1 lane -> replace
// every ds_bpermute with v_mov_b32 dpp wave_shr:1 / wave_shl:1 (VALU pipe,
// ~2cy, no lgkmcnt). LDS-pipe usage drops to ZERO. Same-iteration consumption
// (no deferred q* state) shrinks VGPRs -> SEG=16 gives 5120 waves = 5/SIMD.
#define IMW 512
#define SEG 16
#define NSEG (512/SEG)      // 32
#define NSTRIP 5            // 5*116 = 580 >= 512
#define OUTW 116

__device__ __forceinline__ int reflect512(int i) {   // valid for i in [-511,1022]
    int a = i < 0 ? -i : i;
    int b = 1022 - a;
    return a < b ? a : b;
}
// DPP wave shifts (gfx9-lineage): shr moves data toward higher lanes.
__device__ __forceinline__ float dshr(float v) {  // lane i <- lane i-1 (lane0 <- 0)
    return __int_as_float(__builtin_amdgcn_update_dpp(
        0, __float_as_int(v), 0x138 /*wave_shr:1*/, 0xF, 0xF, true));
}
__device__ __forceinline__ float dshl(float v) {  // lane i <- lane i+1 (lane63 <- 0)
    return __int_as_float(__builtin_amdgcn_update_dpp(
        0, __float_as_int(v), 0x130 /*wave_shl:1*/, 0xF, 0xF, true));
}

__global__ __launch_bounds__(256, 5)
void canny_dpp(const float* __restrict__ x, float* __restrict__ out) {
    const int lane = threadIdx.x & 63;
    const int unit = __builtin_amdgcn_readfirstlane(
                         (int)(blockIdx.x * 4 + (threadIdx.x >> 6)));
    const int img   = unit / (NSTRIP * NSEG);
    const int rem   = unit - img * (NSTRIP * NSEG);
    const int strip = rem / NSEG;
    const int seg   = rem - strip * NSEG;
    const int Y0 = seg * SEG, Y1 = Y0 + SEG;
    const int xbase = strip * OUTW - 6;
    const int xa = xbase + 2 * lane, xb = xa + 1;    // element columns (a even)
    const int xra = reflect512(xa), xrb = reflect512(xb);
    const bool inA = (xa >= 0) && (xa < IMW);
    const bool inB = (xb >= 0) && (xb < IMW);
    const bool stl = (lane >= 3) && (lane < 61) && (xb < IMW);
    const bool clampL = (xa == 0);                   // sobel edge-pad x left
    const bool clampR = (xb == IMW - 1);             // sobel edge-pad x right

    const float* base = x + (size_t)img * 3 * IMW * IMW;
    const float* b0 = base + (size_t)reflect512(Y0 - 6) * IMW;
    const float* b1 = b0 + (size_t)IMW * IMW;
    const float* b2 = b0 + (size_t)2 * IMW * IMW;
    float* ob = out + (size_t)img * IMW * IMW;

    const float K0 = 0.054488684549643f, K1 = 0.244201342003233f, K2 = 0.402619946931554f;

    // ring buffers; row labels at iteration v (after push):
    float h0a=0,h1a=0,h2a=0,h3a=0,h4a=0, h0b=0,h1b=0,h2b=0,h3b=0,h4b=0; // hb rows v-4..v
    float hxA0=0,hxA1=0,hxA2=0, hxB0=0,hxB1=0,hxB2=0;                   // hx rows v-4..v-2
    float hyA0=0,hyA1=0,hyA2=0, hyB0=0,hyB1=0,hyB2=0;
    float mgA0=0,mgA1=0,mgA2=0, mgB0=0,mgB1=0,mgB2=0;                   // mag rows v-5..v-3
    int   axA0=0,axA1=0, axB0=0,axB1=0;                                 // axis rows v-4,v-3
    float cmA0=0,cmA1=0,cmA2=0,cmA3=0,cmA4=0;                           // colmax rows v-8..v-4
    float cmB0=0,cmB1=0,cmB2=0,cmB3=0,cmB4=0;

    // prefetch gray source row v = Y0-6
    float f0a = b0[xra], f0b = b0[xrb];
    float f1a = b1[xra], f1b = b1[xrb];
    float f2a = b2[xra], f2b = b2[xrb];

    #pragma unroll 4
    for (int v = Y0 - 6; v <= Y1 + 5; ++v) {
        // ---- [1] gray row v; advance pointers (reflect walks +-1), prefetch v+1
        float ga = 0.299f * f2a + 0.587f * f1a + 0.114f * f0a;
        float gb = 0.299f * f2b + 0.587f * f1b + 0.114f * f0b;
        const int d = ((unsigned)v <= 510u) ? IMW : -IMW;     // scalar
        b0 += d; b1 += d; b2 += d;
        f0a = b0[xra]; f0b = b0[xrb];
        f1a = b1[xra]; f1b = b1[xrb];
        f2a = b2[xra]; f2b = b2[xrb];

        // ---- [2] h-blur row v (4 DPP shifts)
        // e0 taps x-2,x-1,x+1,x+2 = a(L-1), b(L-1), own b, a(L+1)
        float gam = dshr(ga), gbm = dshr(gb);
        float gap = dshl(ga), gbp = dshl(gb);
        float hba = K0 * (gam + gap) + K1 * (gbm + gb) + K2 * ga;
        float hbb = K0 * (gbm + gbp) + K1 * (ga + gap) + K2 * gb;
        h0a=h1a; h1a=h2a; h2a=h3a; h3a=h4a; h4a=hba;
        h0b=h1b; h1b=h2b; h2b=h3b; h3b=h4b; h4b=hbb;

        // ---- [3] v-blur -> blur row v-2
        float bla = K0 * (h0a + h4a) + K1 * (h1a + h3a) + K2 * h2a;
        float blb = K0 * (h0b + h4b) + K1 * (h1b + h3b) + K2 * h2b;

        // ---- [4] sobel h-pass row v-2 (2 DPP shifts, edge-clamped x)
        {
            float blbm = dshr(blb);            // b(L-1) = left of e0
            float blap = dshl(bla);            // a(L+1) = right of e1
            float la = clampL ? bla : blbm;
            float ra = blb;
            float lb = bla;
            float rb = clampR ? blb : blap;
            float nxa = ra - la, nya = la + 2.f * bla + ra;
            float nxb = rb - lb, nyb = lb + 2.f * blb + rb;
            hxA0=hxA1; hxA1=hxA2; hxA2=nxa;  hxB0=hxB1; hxB1=hxB2; hxB2=nxb;
            hyA0=hyA1; hyA1=hyA2; hyA2=nya;  hyB0=hyB1; hyB1=hyB2; hyB2=nyb;
        }

        // ---- [5] sobel v-pass at g = v-3 -> mag/axis; push rings
        {
            const int g = v - 3;
            float hxaa = (g==0) ? hxA1 : hxA0;  float hxca = (g==511) ? hxA1 : hxA2;
            float hyaa = (g==0) ? hyA1 : hyA0;  float hyca = (g==511) ? hyA1 : hyA2;
            float gxa = (hxaa + 2.f * hxA1 + hxca) * 0.125f;
            float gya = (hyca - hyaa) * 0.125f;
            float maga = sqrtf(gxa * gxa + gya * gya + 1e-6f);
            float axma = fabsf(gxa), ayma = fabsf(gya);
            int aa;
            if (ayma <= 0.41421356237309515f * axma)      aa = 0;
            else if (ayma >= 2.4142135623730951f * axma)  aa = 2;
            else aa = ((gxa >= 0.f) == (gya >= 0.f)) ? 1 : 3;

            float hxab = (g==0) ? hxB1 : hxB0;  float hxcb = (g==511) ? hxB1 : hxB2;
            float hyab = (g==0) ? hyB1 : hyB0;  float hycb = (g==511) ? hyB1 : hyB2;
            float gxb = (hxab + 2.f * hxB1 + hxcb) * 0.125f;
            float gyb = (hycb - hyab) * 0.125f;
            float magb = sqrtf(gxb * gxb + gyb * gyb + 1e-6f);
            float axmb = fabsf(gxb), aymb = fabsf(gyb);
            int ab;
            if (aymb <= 0.41421356237309515f * axmb)      ab = 0;
            else if (aymb >= 2.4142135623730951f * axmb)  ab = 2;
            else ab = ((gxb >= 0.f) == (gyb >= 0.f)) ? 1 : 3;

            mgA0=mgA1; mgA1=mgA2; mgA2 = inA ? maga : 0.f;
            mgB0=mgB1; mgB1=mgB2; mgB2 = inB ? magb : 0.f;
            axA0=axA1; axA1=aa;
            axB0=axB1; axB1=ab;
        }

        // ---- [6] NMS at m = v-4 (6 DPP shifts) + [7] colmax (4 DPP shifts)
        {
            const int m = v - 4;
            float m0a = (m==0)?0.f:mgA0,   m0b = (m==0)?0.f:mgB0;     // row m-1
            float m2a = (m==511)?0.f:mgA2, m2b = (m==511)?0.f:mgB2;   // row m+1
            // x-1 neighbors for e0 (B at L-1), x+1 neighbors for e1 (A at L+1)
            float l1 = dshr(mgB1), l0 = dshr(m0b), l2 = dshr(m2b);
            float r1 = dshl(mgA1), r0 = dshl(m0a), r2 = dshl(m2a);
            // element a (center mgA1, axis axA0 = row m)
            const int da = axA0;
            float mpa = (da==0) ? mgB1 : (da==1) ? m2b : (da==2) ? m2a : l2;
            float mna = (da==0) ? l1   : (da==1) ? l0  : (da==2) ? m0a : m0b;
            float cena = mgA1;
            float mska = (inA && fminf(cena - mpa, cena - mna) > 0.f) ? cena : 0.f;
            // element b (center mgB1, axis axB0)
            const int db = axB0;
            float mpb = (db==0) ? r1  : (db==1) ? r2  : (db==2) ? m2b : m2a;
            float mnb = (db==0) ? mgA1: (db==1) ? m0a : (db==2) ? m0b : r0;
            float cenb = mgB1;
            float mskb = (inB && fminf(cenb - mpb, cenb - mnb) > 0.f) ? cenb : 0.f;

            // colmax row m: e0 taps a(L-1),b(L-1),a,b,a(L+1); e1 shifted by one
            float sam = dshr(mska), sbm = dshr(mskb);
            float sap = dshl(mska), sbp = dshl(mskb);
            float cma = fmaxf(fmaxf(sam, sbm), fmaxf(fmaxf(mska, mskb), sap));
            float cmb = fmaxf(fmaxf(sbm, mska), fmaxf(fmaxf(mskb, sap), sbp));
            cmA0=cmA1; cmA1=cmA2; cmA2=cmA3; cmA3=cmA4; cmA4=cma;
            cmB0=cmB1; cmB1=cmB2; cmB2=cmB3; cmB3=cmB4; cmB4=cmb;
        }

        // ---- [8] out row y = v-6 (vertical 5-max, zero-pad y)
        {
            const int y = v - 6;
            if (y >= Y0) {
                float c0a=(y>=2)?cmA0:0.f, c1a=(y>=1)?cmA1:0.f;
                float c3a=(y<=510)?cmA3:0.f, c4a=(y<=509)?cmA4:0.f;
                float va = fmaxf(fmaxf(fmaxf(c0a, c1a), fmaxf(cmA2, c3a)), c4a);
                float c0b=(y>=2)?cmB0:0.f, c1b=(y>=1)?cmB1:0.f;
                float c3b=(y<=510)?cmB3:0.f, c4b=(y<=509)?cmB4:0.f;
                float vb = fmaxf(fmaxf(fmaxf(c0b, c1b), fmaxf(cmB2, c3b)), c4b);
                if (stl) {
                    float2 t; t.x = va; t.y = vb;
                    *(float2*)(ob + (size_t)y * IMW + xa) = t;
                }
            }
        }
    }
}

extern "C" void kernel_launch(void* const* d_in, const int* in_sizes, int n_in,
                              void* d_out, int out_size, void* d_ws, size_t ws_size,
                              hipStream_t stream) {
    const float* x = (const float*)d_in[0];
    float* out = (float*)d_out;
    const int units = 32 * NSTRIP * NSEG;   // 5120 waves
    dim3 grid(units / 4);                   // 4 waves per 256-thread block
    canny_dpp<<<grid, 256, 0, stream>>>(x, out);
}

// Round 5
// 177.154 us; speedup vs baseline: 1.0129x; 1.0026x over previous
//
#include <hip/hip_runtime.h>
#include <math.h>

// Round 7: latency attack. Depth-2 explicit prefetch ring (loads for row v+2
// issued at iter v, compile-time slot index) + template<bool EDGE> boundary
// peeling: 30/32 segments run a fast loop with zero row-boundary selects,
// constant +IMW pointer walk, and unguarded steady-state stores.
#define IMW 512
#define SEG 16
#define NSEG (512/SEG)      // 32
#define NSTRIP 5            // 5*116 = 580 >= 512
#define OUTW 116

__device__ __forceinline__ int reflect512(int i) {   // valid for i in [-511,1022]
    int a = i < 0 ? -i : i;
    int b = 1022 - a;
    return a < b ? a : b;
}
// DPP wave shifts (gfx9-lineage): shr moves data toward higher lanes.
__device__ __forceinline__ float dshr(float v) {  // lane i <- lane i-1 (lane0 <- 0)
    return __int_as_float(__builtin_amdgcn_update_dpp(
        0, __float_as_int(v), 0x138 /*wave_shr:1*/, 0xF, 0xF, true));
}
__device__ __forceinline__ float dshl(float v) {  // lane i <- lane i+1 (lane63 <- 0)
    return __int_as_float(__builtin_amdgcn_update_dpp(
        0, __float_as_int(v), 0x130 /*wave_shl:1*/, 0xF, 0xF, true));
}

struct IC0 { static constexpr int value = 0; };
struct IC1 { static constexpr int value = 1; };
struct CT  { static constexpr bool value = true;  };
struct CF  { static constexpr bool value = false; };

template<bool EDGE>
__device__ __forceinline__ void run_strip(
    const float* b0, const float* b1, const float* b2, float* ob,
    const int Y0, const int Y1, const int xra, const int xrb, const int xa,
    const bool inA, const bool inB, const bool stl,
    const bool clampL, const bool clampR)
{
    const float K0 = 0.054488684549643f, K1 = 0.244201342003233f, K2 = 0.402619946931554f;

    // ring buffers; row labels at iteration v (after push):
    float h0a=0,h1a=0,h2a=0,h3a=0,h4a=0, h0b=0,h1b=0,h2b=0,h3b=0,h4b=0; // hb rows v-4..v
    float hxA0=0,hxA1=0,hxA2=0, hxB0=0,hxB1=0,hxB2=0;                   // hx rows v-4..v-2
    float hyA0=0,hyA1=0,hyA2=0, hyB0=0,hyB1=0,hyB2=0;
    float mgA0=0,mgA1=0,mgA2=0, mgB0=0,mgB1=0,mgB2=0;                   // mag rows v-5..v-3
    int   axA0=0,axA1=0, axB0=0,axB1=0;                                 // axis rows v-4,v-3
    float cmA0=0,cmA1=0,cmA2=0,cmA3=0,cmA4=0;                           // colmax rows v-8..v-4
    float cmB0=0,cmB1=0,cmB2=0,cmB3=0,cmB4=0;

    // depth-2 prefetch ring: slot S holds row (v) when consumed at iter v
    float f0a[2], f0b[2], f1a[2], f1b[2], f2a[2], f2b[2];

    // prologue: load rows Y0-6 (slot0) and Y0-5 (slot1); advance pointers
    f0a[0]=b0[xra]; f0b[0]=b0[xrb];
    f1a[0]=b1[xra]; f1b[0]=b1[xrb];
    f2a[0]=b2[xra]; f2b[0]=b2[xrb];
    {
        const int d = EDGE ? (((unsigned)(Y0-6) <= 510u) ? IMW : -IMW) : IMW;
        b0 += d; b1 += d; b2 += d;
    }
    f0a[1]=b0[xra]; f0b[1]=b0[xrb];
    f1a[1]=b1[xra]; f1b[1]=b1[xrb];
    f2a[1]=b2[xra]; f2b[1]=b2[xrb];
    {
        const int d = EDGE ? (((unsigned)(Y0-5) <= 510u) ? IMW : -IMW) : IMW;
        b0 += d; b1 += d; b2 += d;
    }

    auto iter = [&](int v, auto sc, auto st) {
        constexpr int  S  = decltype(sc)::value;
        constexpr bool ST = decltype(st)::value;

        // ---- [1] gray row v from slot S; refill slot S with row v+2
        float ga = 0.299f * f2a[S] + 0.587f * f1a[S] + 0.114f * f0a[S];
        float gb = 0.299f * f2b[S] + 0.587f * f1b[S] + 0.114f * f0b[S];
        f0a[S]=b0[xra]; f0b[S]=b0[xrb];
        f1a[S]=b1[xra]; f1b[S]=b1[xrb];
        f2a[S]=b2[xra]; f2b[S]=b2[xrb];
        if constexpr (EDGE) {
            const int d = ((unsigned)(v+2) <= 510u) ? IMW : -IMW;
            b0 += d; b1 += d; b2 += d;
        } else {
            b0 += IMW; b1 += IMW; b2 += IMW;
        }

        // ---- [2] h-blur row v (4 DPP shifts)
        float gam = dshr(ga), gbm = dshr(gb);
        float gap = dshl(ga), gbp = dshl(gb);
        float hba = K0 * (gam + gap) + K1 * (gbm + gb) + K2 * ga;
        float hbb = K0 * (gbm + gbp) + K1 * (ga + gap) + K2 * gb;
        h0a=h1a; h1a=h2a; h2a=h3a; h3a=h4a; h4a=hba;
        h0b=h1b; h1b=h2b; h2b=h3b; h3b=h4b; h4b=hbb;

        // ---- [3] v-blur -> blur row v-2
        float bla = K0 * (h0a + h4a) + K1 * (h1a + h3a) + K2 * h2a;
        float blb = K0 * (h0b + h4b) + K1 * (h1b + h3b) + K2 * h2b;

        // ---- [4] sobel h-pass row v-2 (2 DPP shifts, edge-clamped x)
        {
            float blbm = dshr(blb);            // b(L-1) = left of e0
            float blap = dshl(bla);            // a(L+1) = right of e1
            float la = clampL ? bla : blbm;
            float ra = blb;
            float lb = bla;
            float rb = clampR ? blb : blap;
            float nxa = ra - la, nya = la + 2.f * bla + ra;
            float nxb = rb - lb, nyb = lb + 2.f * blb + rb;
            hxA0=hxA1; hxA1=hxA2; hxA2=nxa;  hxB0=hxB1; hxB1=hxB2; hxB2=nxb;
            hyA0=hyA1; hyA1=hyA2; hyA2=nya;  hyB0=hyB1; hyB1=hyB2; hyB2=nyb;
        }

        // ---- [5] sobel v-pass at g = v-3 -> mag/axis; push rings
        {
            float hxaa, hxca, hyaa, hyca, hxab, hxcb, hyab, hycb;
            if constexpr (EDGE) {
                const int g = v - 3;
                hxaa = (g==0) ? hxA1 : hxA0;  hxca = (g==511) ? hxA1 : hxA2;
                hyaa = (g==0) ? hyA1 : hyA0;  hyca = (g==511) ? hyA1 : hyA2;
                hxab = (g==0) ? hxB1 : hxB0;  hxcb = (g==511) ? hxB1 : hxB2;
                hyab = (g==0) ? hyB1 : hyB0;  hycb = (g==511) ? hyB1 : hyB2;
            } else {
                hxaa = hxA0; hxca = hxA2; hyaa = hyA0; hyca = hyA2;
                hxab = hxB0; hxcb = hxB2; hyab = hyB0; hycb = hyB2;
            }
            float gxa = (hxaa + 2.f * hxA1 + hxca) * 0.125f;
            float gya = (hyca - hyaa) * 0.125f;
            float maga = sqrtf(gxa * gxa + gya * gya + 1e-6f);
            float axma = fabsf(gxa), ayma = fabsf(gya);
            int aa;
            if (ayma <= 0.41421356237309515f * axma)      aa = 0;
            else if (ayma >= 2.4142135623730951f * axma)  aa = 2;
            else aa = ((gxa >= 0.f) == (gya >= 0.f)) ? 1 : 3;

            float gxb = (hxab + 2.f * hxB1 + hxcb) * 0.125f;
            float gyb = (hycb - hyab) * 0.125f;
            float magb = sqrtf(gxb * gxb + gyb * gyb + 1e-6f);
            float axmb = fabsf(gxb), aymb = fabsf(gyb);
            int ab;
            if (aymb <= 0.41421356237309515f * axmb)      ab = 0;
            else if (aymb >= 2.4142135623730951f * axmb)  ab = 2;
            else ab = ((gxb >= 0.f) == (gyb >= 0.f)) ? 1 : 3;

            mgA0=mgA1; mgA1=mgA2; mgA2 = inA ? maga : 0.f;
            mgB0=mgB1; mgB1=mgB2; mgB2 = inB ? magb : 0.f;
            axA0=axA1; axA1=aa;
            axB0=axB1; axB1=ab;
        }

        // ---- [6] NMS at m = v-4 (6 DPP) + [7] colmax (4 DPP)
        {
            float m0a, m0b, m2a, m2b;
            if constexpr (EDGE) {
                const int m = v - 4;
                m0a = (m==0)?0.f:mgA0;   m0b = (m==0)?0.f:mgB0;     // row m-1
                m2a = (m==511)?0.f:mgA2; m2b = (m==511)?0.f:mgB2;   // row m+1
            } else {
                m0a = mgA0; m0b = mgB0; m2a = mgA2; m2b = mgB2;
            }
            float l1 = dshr(mgB1), l0 = dshr(m0b), l2 = dshr(m2b);
            float r1 = dshl(mgA1), r0 = dshl(m0a), r2 = dshl(m2a);
            // element a (center mgA1, axis axA0 = row m)
            const int da = axA0;
            float mpa = (da==0) ? mgB1 : (da==1) ? m2b : (da==2) ? m2a : l2;
            float mna = (da==0) ? l1   : (da==1) ? l0  : (da==2) ? m0a : m0b;
            float cena = mgA1;
            float mska = (inA && fminf(cena - mpa, cena - mna) > 0.f) ? cena : 0.f;
            // element b (center mgB1, axis axB0)
            const int db = axB0;
            float mpb = (db==0) ? r1  : (db==1) ? r2  : (db==2) ? m2b : m2a;
            float mnb = (db==0) ? mgA1: (db==1) ? m0a : (db==2) ? m0b : r0;
            float cenb = mgB1;
            float mskb = (inB && fminf(cenb - mpb, cenb - mnb) > 0.f) ? cenb : 0.f;

            // colmax row m
            float sam = dshr(mska), sbm = dshr(mskb);
            float sap = dshl(mska), sbp = dshl(mskb);
            float cma = fmaxf(fmaxf(sam, sbm), fmaxf(fmaxf(mska, mskb), sap));
            float cmb = fmaxf(fmaxf(sbm, mska), fmaxf(fmaxf(mskb, sap), sbp));
            cmA0=cmA1; cmA1=cmA2; cmA2=cmA3; cmA3=cmA4; cmA4=cma;
            cmB0=cmB1; cmB1=cmB2; cmB2=cmB3; cmB3=cmB4; cmB4=cmb;
        }

        // ---- [8] out row y = v-6 (vertical 5-max)
        if constexpr (ST) {
            const int y = v - 6;
            bool doSt = true;
            if constexpr (EDGE) doSt = (y >= Y0);
            if (doSt) {
                float c0a, c1a, c3a, c4a, c0b, c1b, c3b, c4b;
                if constexpr (EDGE) {
                    c0a=(y>=2)?cmA0:0.f; c1a=(y>=1)?cmA1:0.f;
                    c3a=(y<=510)?cmA3:0.f; c4a=(y<=509)?cmA4:0.f;
                    c0b=(y>=2)?cmB0:0.f; c1b=(y>=1)?cmB1:0.f;
                    c3b=(y<=510)?cmB3:0.f; c4b=(y<=509)?cmB4:0.f;
                } else {
                    c0a=cmA0; c1a=cmA1; c3a=cmA3; c4a=cmA4;
                    c0b=cmB0; c1b=cmB1; c3b=cmB3; c4b=cmB4;
                }
                float va = fmaxf(fmaxf(fmaxf(c0a, c1a), fmaxf(cmA2, c3a)), c4a);
                float vb = fmaxf(fmaxf(fmaxf(c0b, c1b), fmaxf(cmB2, c3b)), c4b);
                if (stl) {
                    float2 t; t.x = va; t.y = vb;
                    *(float2*)(ob + (size_t)y * IMW + xa) = t;
                }
            }
        }
    };

    if constexpr (!EDGE) {
        // warmup: v = Y0-6 .. Y0+5 (12 iters), no store
        #pragma unroll 2
        for (int v = Y0 - 6; v < Y0 + 6; v += 2) {
            iter(v, IC0{}, CF{});
            iter(v + 1, IC1{}, CF{});
        }
        // steady: v = Y0+6 .. Y1+5 (16 iters), always store
        #pragma unroll 2
        for (int v = Y0 + 6; v < Y1 + 6; v += 2) {
            iter(v, IC0{}, CT{});
            iter(v + 1, IC1{}, CT{});
        }
    } else {
        #pragma unroll 1
        for (int v = Y0 - 6; v < Y1 + 6; v += 2) {
            iter(v, IC0{}, CT{});
            iter(v + 1, IC1{}, CT{});
        }
    }
}

__global__ __launch_bounds__(256, 5)
void canny_dpp2(const float* __restrict__ x, float* __restrict__ out) {
    const int lane = threadIdx.x & 63;
    const int unit = __builtin_amdgcn_readfirstlane(
                         (int)(blockIdx.x * 4 + (threadIdx.x >> 6)));
    const int img   = unit / (NSTRIP * NSEG);
    const int rem   = unit - img * (NSTRIP * NSEG);
    const int strip = rem / NSEG;
    const int seg   = rem - strip * NSEG;
    const int Y0 = seg * SEG, Y1 = Y0 + SEG;
    const int xbase = strip * OUTW - 6;
    const int xa = xbase + 2 * lane, xb = xa + 1;    // element columns (a even)
    const int xra = reflect512(xa), xrb = reflect512(xb);
    const bool inA = (xa >= 0) && (xa < IMW);
    const bool inB = (xb >= 0) && (xb < IMW);
    const bool stl = (lane >= 3) && (lane < 61) && (xb < IMW);
    const bool clampL = (xa == 0);                   // sobel edge-pad x left
    const bool clampR = (xb == IMW - 1);             // sobel edge-pad x right

    const float* base = x + (size_t)img * 3 * IMW * IMW;
    const float* b0 = base + (size_t)reflect512(Y0 - 6) * IMW;
    const float* b1 = b0 + (size_t)IMW * IMW;
    const float* b2 = b0 + (size_t)2 * IMW * IMW;
    float* ob = out + (size_t)img * IMW * IMW;

    if (seg == 0 || seg == NSEG - 1) {
        run_strip<true >(b0, b1, b2, ob, Y0, Y1, xra, xrb, xa,
                         inA, inB, stl, clampL, clampR);
    } else {
        run_strip<false>(b0, b1, b2, ob, Y0, Y1, xra, xrb, xa,
                         inA, inB, stl, clampL, clampR);
    }
}

extern "C" void kernel_launch(void* const* d_in, const int* in_sizes, int n_in,
                              void* d_out, int out_size, void* d_ws, size_t ws_size,
                              hipStream_t stream) {
    const float* x = (const float*)d_in[0];
    float* out = (float*)d_out;
    const int units = 32 * NSTRIP * NSEG;   // 5120 waves
    dim3 grid(units / 4);                   // 4 waves per 256-thread block
    canny_dpp2<<<grid, 256, 0, stream>>>(x, out);
}